// Round 9
// baseline (312.167 us; speedup 1.0000x reference)
//
#include <hip/hip_runtime.h>
#include <math.h>

#define Ss 1024
#define Dd 1024
#define Hh 16
#define Kk 64

typedef __bf16 bf16x8 __attribute__((ext_vector_type(8)));
typedef __bf16 bf16x4 __attribute__((ext_vector_type(4)));
typedef float  f32x4  __attribute__((ext_vector_type(4)));

#define MFMA16(a, b, c) __builtin_amdgcn_mfma_f32_16x16x32_bf16(a, b, c, 0, 0, 0)

// ws element offsets (bf16 units): xb | WT | WoT | qb | kb | vb | ctxb
#define XB_E   8388608u
#define WT_E   3145728u
#define WOT_E  1048576u
#define QKV_E  8388608u

// ---------------------------------------------------------------------------
// prep: z<4 -> transpose+cast weight matrix z; z==4 -> cast x to bf16
// ---------------------------------------------------------------------------
__global__ __launch_bounds__(256) void prep(
    const float* __restrict__ x,
    const float* __restrict__ Wq, const float* __restrict__ Wk,
    const float* __restrict__ Wv, const float* __restrict__ Wo,
    __bf16* __restrict__ xb, __bf16* __restrict__ WT, __bf16* __restrict__ WoT)
{
    __shared__ float tile[64][65];
    const int z = blockIdx.z;
    const int t = threadIdx.x;

    if (z == 4) {   // x cast
        size_t blk = blockIdx.y * 16 + blockIdx.x;
        const float4* src = (const float4*)(x + blk * 32768);
        bf16x4* dst = (bf16x4*)(xb + blk * 32768);
        #pragma unroll
        for (int u = 0; u < 32; ++u) {
            float4 v = src[u * 256 + t];
            dst[u * 256 + t] =
                (bf16x4){(__bf16)v.x, (__bf16)v.y, (__bf16)v.z, (__bf16)v.w};
        }
        return;
    }

    const float* src = (z == 0) ? Wq : (z == 1) ? Wk : (z == 2) ? Wv : Wo;
    __bf16* dst = (z < 3) ? (WT + (size_t)z * 1048576) : WoT;

    int r0 = blockIdx.y * 64, c0 = blockIdx.x * 64;
    int rr = t >> 2, cg = (t & 3) * 16;

    #pragma unroll
    for (int u = 0; u < 4; ++u) {
        float4 v = *(const float4*)(src + (size_t)(r0 + rr) * 1024 + c0 + cg + u * 4);
        tile[rr][cg + u * 4 + 0] = v.x;
        tile[rr][cg + u * 4 + 1] = v.y;
        tile[rr][cg + u * 4 + 2] = v.z;
        tile[rr][cg + u * 4 + 3] = v.w;
    }
    __syncthreads();
    bf16x8 o0, o1;
    #pragma unroll
    for (int jj = 0; jj < 8; ++jj) o0[jj] = (__bf16)tile[cg + jj][rr];
    #pragma unroll
    for (int jj = 0; jj < 8; ++jj) o1[jj] = (__bf16)tile[cg + 8 + jj][rr];
    __bf16* dp = dst + (size_t)(c0 + rr) * 1024 + r0 + cg;
    *(bf16x8*)dp = o0;
    *(bf16x8*)(dp + 8) = o1;
}

// ---------------------------------------------------------------------------
// Fused QKV GEMM: grid (8,64,3), z = matrix. ONE MFMA orientation (swapped:
// D[n=ch][m=token]) for all z — round 7 showed dual orientations cost 40
// VGPRs. Q/K: vectorized bf16x4 epilogue. V: scalar stores into [ch][s]
// (once per block, epilogue-only cost). 128x128 tile, BK=32, ping-pong LDS.
// ---------------------------------------------------------------------------
__global__ __launch_bounds__(256) void gemm_qkv(
    const __bf16* __restrict__ A, const __bf16* __restrict__ WT,
    __bf16* __restrict__ qb, __bf16* __restrict__ kb, __bf16* __restrict__ vb,
    const float* __restrict__ bq, const float* __restrict__ bk,
    const float* __restrict__ bv)
{
    __shared__ __align__(16) __bf16 As[2][128][32];
    __shared__ __align__(16) __bf16 Bs[2][128][32];

    const int t = threadIdx.x;
    const int wave = t >> 6, lane = t & 63;
    const int quad = lane >> 4, l16 = lane & 15;
    const int wm = wave >> 1, wn = wave & 1;
    const int m0 = blockIdx.y * 128, n0 = blockIdx.x * 128;
    const int z = blockIdx.z;
    const __bf16* Bt = WT + (size_t)z * 1048576;

    const int sr = t >> 2;
    const int sc = (t & 3) * 8;

    f32x4 acc[4][4];
    #pragma unroll
    for (int i = 0; i < 4; ++i)
        #pragma unroll
        for (int j = 0; j < 4; ++j) acc[i][j] = (f32x4){0.f, 0.f, 0.f, 0.f};

    const __bf16* pa0 = A + (size_t)(m0 + sr) * 1024 + sc;
    const __bf16* pa1 = A + (size_t)(m0 + sr + 64) * 1024 + sc;
    const __bf16* pb0 = Bt + (size_t)(n0 + sr) * 1024 + sc;
    const __bf16* pb1 = Bt + (size_t)(n0 + sr + 64) * 1024 + sc;

    bf16x8 ra0 = *(const bf16x8*)(pa0);
    bf16x8 ra1 = *(const bf16x8*)(pa1);
    bf16x8 rb0 = *(const bf16x8*)(pb0);
    bf16x8 rb1 = *(const bf16x8*)(pb1);

    for (int k0 = 0; k0 < 1024; k0 += 32) {
        const int p = (k0 >> 5) & 1;
        *(bf16x8*)&As[p][sr][sc] = ra0;
        *(bf16x8*)&As[p][sr + 64][sc] = ra1;
        *(bf16x8*)&Bs[p][sr][sc] = rb0;
        *(bf16x8*)&Bs[p][sr + 64][sc] = rb1;
        __syncthreads();

        const int kn = k0 + 32;
        if (kn < 1024) {
            ra0 = *(const bf16x8*)(pa0 + kn);
            ra1 = *(const bf16x8*)(pa1 + kn);
            rb0 = *(const bf16x8*)(pb0 + kn);
            rb1 = *(const bf16x8*)(pb1 + kn);
        }

        bf16x8 af[4], bfr[4];
        #pragma unroll
        for (int i = 0; i < 4; ++i)
            af[i] = *(const bf16x8*)&As[p][wm * 64 + i * 16 + l16][quad * 8];
        #pragma unroll
        for (int j = 0; j < 4; ++j)
            bfr[j] = *(const bf16x8*)&Bs[p][wn * 64 + j * 16 + l16][quad * 8];
        #pragma unroll
        for (int i = 0; i < 4; ++i)
            #pragma unroll
            for (int j = 0; j < 4; ++j)
                acc[i][j] = MFMA16(bfr[j], af[i], acc[i][j]);   // D[n=ch][m=tok]
    }

    const float* bias = (z == 0) ? bq : (z == 1) ? bk : bv;
    const int h = (n0 >> 6) + wn;
    if (z < 2) {
        __bf16* dst0 = (z == 0) ? qb : kb;
        const float sc2 = (z == 0) ? 0.125f : 1.0f;
        #pragma unroll
        for (int i = 0; i < 4; ++i) {
            int m = m0 + wm * 64 + i * 16 + l16;
            int b = m >> 10, s = m & 1023;
            __bf16* dst = dst0 + ((size_t)(b * Hh + h) * Ss + s) * Kk;
            #pragma unroll
            for (int j = 0; j < 4; ++j) {
                int ch0 = j * 16 + quad * 4;
                float4 b4 = *(const float4*)(bias + n0 + wn * 64 + ch0);
                bf16x4 o;
                o[0] = (__bf16)((acc[i][j][0] + b4.x) * sc2);
                o[1] = (__bf16)((acc[i][j][1] + b4.y) * sc2);
                o[2] = (__bf16)((acc[i][j][2] + b4.z) * sc2);
                o[3] = (__bf16)((acc[i][j][3] + b4.w) * sc2);
                *(bf16x4*)(dst + ch0) = o;
            }
        }
    } else {
        // V -> [bh][ch][s]; swapped C has ch in regs -> scalar stores (64),
        // lane-coalesced along s (l16 = 16 consecutive tokens).
        #pragma unroll
        for (int i = 0; i < 4; ++i) {
            int m = m0 + wm * 64 + i * 16 + l16;
            int b = m >> 10, s = m & 1023;
            __bf16* dstv = vb + (size_t)(b * Hh + h) * Kk * Ss + s;
            #pragma unroll
            for (int j = 0; j < 4; ++j) {
                int ch0 = j * 16 + quad * 4;
                float4 b4 = *(const float4*)(bias + n0 + wn * 64 + ch0);
                dstv[(size_t)(ch0 + 0) * Ss] = (__bf16)(acc[i][j][0] + b4.x);
                dstv[(size_t)(ch0 + 1) * Ss] = (__bf16)(acc[i][j][1] + b4.y);
                dstv[(size_t)(ch0 + 2) * Ss] = (__bf16)(acc[i][j][2] + b4.z);
                dstv[(size_t)(ch0 + 3) * Ss] = (__bf16)(acc[i][j][3] + b4.w);
            }
        }
    }
}

// ---------------------------------------------------------------------------
// Output projection GEMM (swapped orientation, float4 stores). 128x128, BK=32.
// ---------------------------------------------------------------------------
__global__ __launch_bounds__(256) void gemm_out(
    const __bf16* __restrict__ A, const __bf16* __restrict__ Bt,
    const float* __restrict__ bo, float* __restrict__ outf)
{
    __shared__ __align__(16) __bf16 As[2][128][32];
    __shared__ __align__(16) __bf16 Bs[2][128][32];

    const int t = threadIdx.x;
    const int wave = t >> 6, lane = t & 63;
    const int quad = lane >> 4, l16 = lane & 15;
    const int wm = wave >> 1, wn = wave & 1;
    const int m0 = blockIdx.y * 128, n0 = blockIdx.x * 128;

    const int sr = t >> 2;
    const int sc = (t & 3) * 8;

    f32x4 acc[4][4];
    #pragma unroll
    for (int i = 0; i < 4; ++i)
        #pragma unroll
        for (int j = 0; j < 4; ++j) acc[i][j] = (f32x4){0.f, 0.f, 0.f, 0.f};

    const __bf16* pa0 = A + (size_t)(m0 + sr) * 1024 + sc;
    const __bf16* pa1 = A + (size_t)(m0 + sr + 64) * 1024 + sc;
    const __bf16* pb0 = Bt + (size_t)(n0 + sr) * 1024 + sc;
    const __bf16* pb1 = Bt + (size_t)(n0 + sr + 64) * 1024 + sc;

    bf16x8 ra0 = *(const bf16x8*)(pa0);
    bf16x8 ra1 = *(const bf16x8*)(pa1);
    bf16x8 rb0 = *(const bf16x8*)(pb0);
    bf16x8 rb1 = *(const bf16x8*)(pb1);

    for (int k0 = 0; k0 < 1024; k0 += 32) {
        const int p = (k0 >> 5) & 1;
        *(bf16x8*)&As[p][sr][sc] = ra0;
        *(bf16x8*)&As[p][sr + 64][sc] = ra1;
        *(bf16x8*)&Bs[p][sr][sc] = rb0;
        *(bf16x8*)&Bs[p][sr + 64][sc] = rb1;
        __syncthreads();

        const int kn = k0 + 32;
        if (kn < 1024) {
            ra0 = *(const bf16x8*)(pa0 + kn);
            ra1 = *(const bf16x8*)(pa1 + kn);
            rb0 = *(const bf16x8*)(pb0 + kn);
            rb1 = *(const bf16x8*)(pb1 + kn);
        }

        bf16x8 af[4], bfr[4];
        #pragma unroll
        for (int i = 0; i < 4; ++i)
            af[i] = *(const bf16x8*)&As[p][wm * 64 + i * 16 + l16][quad * 8];
        #pragma unroll
        for (int j = 0; j < 4; ++j)
            bfr[j] = *(const bf16x8*)&Bs[p][wn * 64 + j * 16 + l16][quad * 8];
        #pragma unroll
        for (int i = 0; i < 4; ++i)
            #pragma unroll
            for (int j = 0; j < 4; ++j)
                acc[i][j] = MFMA16(bfr[j], af[i], acc[i][j]);
    }

    #pragma unroll
    for (int i = 0; i < 4; ++i) {
        int m = m0 + wm * 64 + i * 16 + l16;
        #pragma unroll
        for (int j = 0; j < 4; ++j) {
            int n = n0 + wn * 64 + j * 16 + quad * 4;
            float4 b4 = *(const float4*)(bo + n);
            float4 o;
            o.x = acc[i][j][0] + b4.x;
            o.y = acc[i][j][1] + b4.y;
            o.z = acc[i][j][2] + b4.z;
            o.w = acc[i][j][3] + b4.w;
            *(float4*)(outf + (size_t)m * 1024 + n) = o;
        }
    }
}

// ---------------------------------------------------------------------------
// Flash attention v4: S^T orientation (MFMA(K,Q): C lane = q, regs = s_k).
// P writes are bf16x4 (was 32 scalar b16), P reads b128, l-sum in-lane.
// Mask folded into exponent: p = exp((s + pen_k) * mq), pen_k in {0,-100}:
//   mq=0 -> p=1 all keys (matches reference -1e9 absorption / uniform row);
//   mk=0 -> p ~ e^(s-100) ~ 1e-43, negligible vs O(1) unmasked terms.
// ---------------------------------------------------------------------------
__global__ __launch_bounds__(256) void attn(
    const __bf16* __restrict__ qb, const __bf16* __restrict__ kb,
    const __bf16* __restrict__ vb, const int* __restrict__ mask,
    __bf16* __restrict__ ctx)
{
    const int bh = blockIdx.x;
    const int q0 = blockIdx.y * 128;
    const int b  = bh >> 4;
    const int h  = bh & 15;
    const size_t base = (size_t)bh * Ss * Kk;

    __shared__ __align__(16) __bf16 Ks[64][72];
    __shared__ __align__(16) __bf16 VTs[64][72];
    __shared__ __align__(16) __bf16 PT[4][32][72];   // [wave][q][s_k]
    __shared__ float penf[1024];

    const int t    = threadIdx.x;
    const int wave = t >> 6, lane = t & 63;
    const int quad = lane >> 4, l16 = lane & 15;
    const int qbase = wave * 32;

    {   // pen = -100 * (1 - mk)
        int4 mi = *(const int4*)(mask + b * Ss + t * 4);
        penf[t * 4 + 0] = (float)(mi.x - 1) * 100.0f;
        penf[t * 4 + 1] = (float)(mi.y - 1) * 100.0f;
        penf[t * 4 + 2] = (float)(mi.z - 1) * 100.0f;
        penf[t * 4 + 3] = (float)(mi.w - 1) * 100.0f;
    }

    const int r0 = t >> 3, c0 = (t & 7) * 8;
    bf16x8 kr0, kr1, vr0, vr1;
    kr0 = *(const bf16x8*)(kb + base + (size_t)(r0) * Kk + c0);
    kr1 = *(const bf16x8*)(kb + base + (size_t)(r0 + 32) * Kk + c0);
    vr0 = *(const bf16x8*)(vb + base + (size_t)(r0) * Ss + c0);
    vr1 = *(const bf16x8*)(vb + base + (size_t)(r0 + 32) * Ss + c0);

    // Q B-fragments direct from global; mq per lane (q = l16 within group)
    bf16x8 bq_[2][2];
    float mq[2];
    #pragma unroll
    for (int qg = 0; qg < 2; ++qg) {
        int q = q0 + qbase + qg * 16 + l16;
        const __bf16* qr = qb + base + (size_t)q * Kk;
        bq_[qg][0] = *(const bf16x8*)(qr + quad * 8);
        bq_[qg][1] = *(const bf16x8*)(qr + 32 + quad * 8);
        mq[qg] = (float)mask[b * Ss + q];
    }

    __syncthreads();   // penf visible

    f32x4 O[2][4];     // O[qg][cb]: lane=q, regs=ch (cb*16+quad*4+r)
    float lsum[2] = {0.f, 0.f};
    #pragma unroll
    for (int qg = 0; qg < 2; ++qg)
        #pragma unroll
        for (int cb = 0; cb < 4; ++cb) O[qg][cb] = (f32x4){0.f, 0.f, 0.f, 0.f};

    for (int kt = 0; kt < Ss; kt += 64) {
        __syncthreads();
        *(bf16x8*)&Ks[r0][c0] = kr0;
        *(bf16x8*)&Ks[r0 + 32][c0] = kr1;
        *(bf16x8*)&VTs[r0][c0] = vr0;
        *(bf16x8*)&VTs[r0 + 32][c0] = vr1;
        __syncthreads();

        int ktn = kt + 64;
        if (ktn < Ss) {
            kr0 = *(const bf16x8*)(kb + base + (size_t)(ktn + r0) * Kk + c0);
            kr1 = *(const bf16x8*)(kb + base + (size_t)(ktn + r0 + 32) * Kk + c0);
            vr0 = *(const bf16x8*)(vb + base + (size_t)(r0) * Ss + ktn + c0);
            vr1 = *(const bf16x8*)(vb + base + (size_t)(r0 + 32) * Ss + ktn + c0);
        }

        // per-reg key penalties (vectorized LDS read)
        f32x4 pv[4];
        #pragma unroll
        for (int nb = 0; nb < 4; ++nb)
            pv[nb] = *(const f32x4*)&penf[kt + nb * 16 + quad * 4];

        // K A-fragments
        bf16x8 ka0[4], ka1[4];
        #pragma unroll
        for (int nb = 0; nb < 4; ++nb) {
            ka0[nb] = *(const bf16x8*)&Ks[nb * 16 + l16][quad * 8];
            ka1[nb] = *(const bf16x8*)&Ks[nb * 16 + l16][32 + quad * 8];
        }

        // S^T: lane = q, rows = s_k (nb*16 + quad*4 + i)
        f32x4 s[2][4];
        #pragma unroll
        for (int qg = 0; qg < 2; ++qg)
            #pragma unroll
            for (int nb = 0; nb < 4; ++nb) {
                f32x4 a = (f32x4){0.f, 0.f, 0.f, 0.f};
                a = MFMA16(ka0[nb], bq_[qg][0], a);
                a = MFMA16(ka1[nb], bq_[qg][1], a);
                s[qg][nb] = a;
            }

        // softmax: p = exp((s + pen)*mq); vectorized P writes along s_k
        #pragma unroll
        for (int qg = 0; qg < 2; ++qg) {
            float ls = 0.f;
            #pragma unroll
            for (int nb = 0; nb < 4; ++nb) {
                bf16x4 p4;
                #pragma unroll
                for (int i = 0; i < 4; ++i) {
                    float p = __expf((s[qg][nb][i] + pv[nb][i]) * mq[qg]);
                    p4[i] = (__bf16)p;
                    ls += p;
                }
                *(bf16x4*)&PT[wave][qg * 16 + l16][nb * 16 + quad * 4] = p4;
            }
            lsum[qg] += ls;
        }

        // P B-fragments (wave-private LDS, in-order, no barrier)
        bf16x8 pb0[2], pb1[2];
        #pragma unroll
        for (int qg = 0; qg < 2; ++qg) {
            pb0[qg] = *(const bf16x8*)&PT[wave][qg * 16 + l16][quad * 8];
            pb1[qg] = *(const bf16x8*)&PT[wave][qg * 16 + l16][32 + quad * 8];
        }
        // PV: O[ch][q] += V^T . P^T
        #pragma unroll
        for (int cb = 0; cb < 4; ++cb) {
            bf16x8 va0 = *(const bf16x8*)&VTs[cb * 16 + l16][quad * 8];
            bf16x8 va1 = *(const bf16x8*)&VTs[cb * 16 + l16][32 + quad * 8];
            #pragma unroll
            for (int qg = 0; qg < 2; ++qg) {
                O[qg][cb] = MFMA16(va0, pb0[qg], O[qg][cb]);
                O[qg][cb] = MFMA16(va1, pb1[qg], O[qg][cb]);
            }
        }
    }

    // l lives per lane (q = l16) split across 4 quads: 2-shuffle reduce
    #pragma unroll
    for (int qg = 0; qg < 2; ++qg) {
        float l = lsum[qg];
        l += __shfl_xor(l, 16);
        l += __shfl_xor(l, 32);
        float inv = 1.0f / l;
        int q = q0 + qbase + qg * 16 + l16;
        __bf16* dst = ctx + ((size_t)(b * Ss + q) * Hh + h) * Kk;
        #pragma unroll
        for (int cb = 0; cb < 4; ++cb) {
            bf16x4 o;
            o[0] = (__bf16)(O[qg][cb][0] * inv);
            o[1] = (__bf16)(O[qg][cb][1] * inv);
            o[2] = (__bf16)(O[qg][cb][2] * inv);
            o[3] = (__bf16)(O[qg][cb][3] * inv);
            *(bf16x4*)(dst + cb * 16 + quad * 4) = o;
        }
    }
}

extern "C" void kernel_launch(void* const* d_in, const int* in_sizes, int n_in,
                              void* d_out, int out_size, void* d_ws, size_t ws_size,
                              hipStream_t stream) {
    const float* x    = (const float*)d_in[0];
    const int*   mask = (const int*)d_in[1];
    const float* Wq   = (const float*)d_in[2];
    const float* bq   = (const float*)d_in[3];
    const float* Wk   = (const float*)d_in[4];
    const float* bk   = (const float*)d_in[5];
    const float* Wv   = (const float*)d_in[6];
    const float* bv   = (const float*)d_in[7];
    const float* Wo   = (const float*)d_in[8];
    const float* bo   = (const float*)d_in[9];

    __bf16* xb   = (__bf16*)d_ws;
    __bf16* WT   = xb + XB_E;
    __bf16* WoT  = WT + WT_E;
    __bf16* qb   = WoT + WOT_E;
    __bf16* kb   = qb + QKV_E;
    __bf16* vb   = kb + QKV_E;
    __bf16* ctxb = vb + QKV_E;
    float* out = (float*)d_out;

    prep<<<dim3(16, 16, 5), 256, 0, stream>>>(x, Wq, Wk, Wv, Wo, xb, WT, WoT);
    gemm_qkv<<<dim3(8, 64, 3), 256, 0, stream>>>(xb, WT, qb, kb, vb, bq, bk, bv);
    attn<<<dim3(128, 8), 256, 0, stream>>>(qb, kb, vb, mask, ctxb);
    gemm_out<<<dim3(8, 64), 256, 0, stream>>>(ctxb, WoT, bo, out);
}